// Round 8
// baseline (272.326 us; speedup 1.0000x reference)
//
#include <hip/hip_runtime.h>

#define BB 4
#define NN 4096
#define CC 128
#define NROWS (BB * NN)   // 16384 rows per tensor

// workspace layout (float offsets) -- R5 layout: 256 partials
#define QN_OFF  0                              // |q_proj| per row (16384)
#define QP_OFF  (QN_OFF + NROWS)               // projected q, 16384 x 128
#define MM_OFF  (QP_OFF + NROWS * CC)          // B x 128 x 128  M = M0 W^T + Ksum b^T
#define KS_OFF  (MM_OFF + BB * CC * CC)        // B x 128  Ksum (sum of khat rows)
#define PP_OFF  (KS_OFF + BB * CC)             // 256 x 16384 partial M0s
#define KP_OFF  (PP_OFF + 256 * CC * CC)       // 256 x 128 partial ksums
#define BAR_OFF (KP_OFF + 256 * CC)            // 2 unsigned barrier counters

#define NBLK 256

__device__ __forceinline__ void fma4(float4& a, const float4 x,
    const float4 w0, const float4 w1, const float4 w2, const float4 w3)
{
    a.x += x.x * w0.x + x.y * w1.x + x.z * w2.x + x.w * w3.x;
    a.y += x.x * w0.y + x.y * w1.y + x.z * w2.y + x.w * w3.y;
    a.z += x.x * w0.z + x.y * w1.z + x.z * w2.z + x.w * w3.z;
    a.w += x.x * w0.w + x.y * w1.w + x.z * w2.w + x.w * w3.w;
}

__device__ __forceinline__ float dot4(const float4 x, const float4 k)
{
    return x.x * k.x + x.y * k.y + x.z * k.z + x.w * k.w;
}

// Manual grid barrier. Safe: grid=256 blocks, LDS 72KB -> HW capacity
// 2 blocks/CU x 256 CUs = 512 >= 256, so all blocks are co-resident and
// the spin cannot deadlock. Counters zeroed by hipMemsetAsync each launch.
__device__ __forceinline__ void grid_barrier(unsigned* ctr)
{
    __syncthreads();
    __threadfence();                       // release: my writes visible
    if (threadIdx.x == 0) {
        atomicAdd(ctr, 1u);
        while (atomicAdd(ctr, 0u) < NBLK) {}
    }
    __syncthreads();
    __threadfence();                       // acquire: see others' writes
}

// ---------------------------------------------------------------------------
// Fused kernel: 256 blocks x 512 threads, all phases in one dispatch.
//   Phase A = R5 projpb (64 q + 64 k rows/block, rank-64 partial M0)
//   Phase B = R5 mchain (reduce 64 partials, build M)
//   Phase C = R5 out    (64 rows/block)
// ---------------------------------------------------------------------------
__global__ __launch_bounds__(512, 2) void fused_kernel(
    const float* __restrict__ q_node, const float* __restrict__ k_node,
    const float* __restrict__ v_node, const float* __restrict__ W,
    const float* __restrict__ bias, float* __restrict__ ws,
    float* __restrict__ out)
{
    __shared__ float S[CC * CC];    // 64 KB, reused by every phase
    __shared__ float4 red[512];     // 8 KB scratch
    unsigned* bar = (unsigned*)(ws + BAR_OFF);

    const int tid = threadIdx.x;
    const int blk = blockIdx.x;     // 0..255

    // ======================= Phase A: projection + partials ================
    {
        for (int e = tid; e < CC * CC; e += 512) {
            int d = e >> 7, c = e & 127;
            S[(c << 7) + ((((d >> 2) ^ (c & 31)) << 2) | (d & 3))] = W[e];
        }

        const int base = blk * 64;
        const int dg = tid & 31;
        const int rg = tid >> 5;        // 0..15, 4 rows each

        float4 bias4 = ((const float4*)bias)[dg];
        float4 acc[8];                  // q0..q3, k0..k3
#pragma unroll
        for (int i = 0; i < 8; i++) acc[i] = bias4;

        __syncthreads();

        const float4* Qv = (const float4*)(q_node + (size_t)(base + rg * 4) * CC);
        const float4* Kv = (const float4*)(k_node + (size_t)(base + rg * 4) * CC);
        const float4* Sv = (const float4*)S;

#define LW(s0, s1, s2, s3, c)                              \
    s0 = Sv[(((c) + 0) << 5) + (dg ^ (((c) + 0) & 31))];   \
    s1 = Sv[(((c) + 1) << 5) + (dg ^ (((c) + 1) & 31))];   \
    s2 = Sv[(((c) + 2) << 5) + (dg ^ (((c) + 2) & 31))];   \
    s3 = Sv[(((c) + 3) << 5) + (dg ^ (((c) + 3) & 31))];
#define LX(xq, xk, c)                                      \
    { const int c4_ = (c) >> 2;                            \
      xq[0] = Qv[c4_];      xq[1] = Qv[32 + c4_];          \
      xq[2] = Qv[64 + c4_]; xq[3] = Qv[96 + c4_];          \
      xk[0] = Kv[c4_];      xk[1] = Kv[32 + c4_];          \
      xk[2] = Kv[64 + c4_]; xk[3] = Kv[96 + c4_]; }
#define FM(w0, w1, w2, w3, xq, xk)                         \
    fma4(acc[0], xq[0], w0, w1, w2, w3);                   \
    fma4(acc[1], xq[1], w0, w1, w2, w3);                   \
    fma4(acc[2], xq[2], w0, w1, w2, w3);                   \
    fma4(acc[3], xq[3], w0, w1, w2, w3);                   \
    fma4(acc[4], xk[0], w0, w1, w2, w3);                   \
    fma4(acc[5], xk[1], w0, w1, w2, w3);                   \
    fma4(acc[6], xk[2], w0, w1, w2, w3);                   \
    fma4(acc[7], xk[3], w0, w1, w2, w3);

        {
            float4 wA0, wA1, wA2, wA3, wB0, wB1, wB2, wB3;
            float4 xqA[4], xkA[4], xqB[4], xkB[4];

            LW(wA0, wA1, wA2, wA3, 0)
            LX(xqA, xkA, 0)
            for (int c = 0; c <= CC - 16; c += 8) {
                LW(wB0, wB1, wB2, wB3, c + 4)
                LX(xqB, xkB, c + 4)
                FM(wA0, wA1, wA2, wA3, xqA, xkA)
                LW(wA0, wA1, wA2, wA3, c + 8)
                LX(xqA, xkA, c + 8)
                FM(wB0, wB1, wB2, wB3, xqB, xkB)
            }
            LW(wB0, wB1, wB2, wB3, CC - 4)
            LX(xqB, xkB, CC - 4)
            FM(wA0, wA1, wA2, wA3, xqA, xkA)
            FM(wB0, wB1, wB2, wB3, xqB, xkB)
        }
#undef LW
#undef LX
#undef FM

        // q rows: store projected row + norm
#pragma unroll
        for (int i = 0; i < 4; i++) {
            const int rq = base + rg * 4 + i;
            float ss = acc[i].x * acc[i].x + acc[i].y * acc[i].y
                     + acc[i].z * acc[i].z + acc[i].w * acc[i].w;
#pragma unroll
            for (int off = 16; off > 0; off >>= 1) ss += __shfl_xor(ss, off, 32);
            ((float4*)(ws + QP_OFF + (size_t)rq * CC))[dg] = acc[i];
            if (dg == 0) ws[QN_OFF + rq] = sqrtf(ss);
        }

        __syncthreads();   // everyone done reading W before LDS reuse

        float* Khs = S;            // 64 x 128 (32 KB)
        float* Vs  = S + 8192;     // 64 x 128 (32 KB)

        // k rows: normalize into LDS
#pragma unroll
        for (int i = 0; i < 4; i++) {
            float ss = acc[4 + i].x * acc[4 + i].x + acc[4 + i].y * acc[4 + i].y
                     + acc[4 + i].z * acc[4 + i].z + acc[4 + i].w * acc[4 + i].w;
#pragma unroll
            for (int off = 16; off > 0; off >>= 1) ss += __shfl_xor(ss, off, 32);
            float inv = 1.0f / sqrtf(ss);
            float4 o = acc[4 + i];
            o.x *= inv; o.y *= inv; o.z *= inv; o.w *= inv;
            ((float4*)(Khs + (rg * 4 + i) * CC))[dg] = o;
        }

        // stage v rows 64x128 (each thread 4 float4)
        const int c4v = tid & 31, nrv = tid >> 5;   // nrv 0..15
        const float* Vp = v_node + (size_t)base * CC;
#pragma unroll
        for (int i = 0; i < 4; i++) {
            int n = nrv + i * 16;
            ((float4*)(Vs + n * CC))[c4v] = ((const float4*)(Vp + (size_t)n * CC))[c4v];
        }
        __syncthreads();

        // partial ksum (column sums of khat)
        float4 ksum4 = make_float4(0.f, 0.f, 0.f, 0.f);
#pragma unroll
        for (int i = 0; i < 4; i++) {
            int n = nrv + i * 16;
            float4 kv = ((const float4*)(Khs + n * CC))[c4v];
            ksum4.x += kv.x; ksum4.y += kv.y; ksum4.z += kv.z; ksum4.w += kv.w;
        }

        // rank-64 outer product, software-pipelined over n
        const int dg2 = tid & 15, cg2 = tid >> 4;    // cg2 0..31
        float a2[4][8];
#pragma unroll
        for (int i = 0; i < 4; i++)
#pragma unroll
            for (int j = 0; j < 8; j++) a2[i][j] = 0.f;

#define P2L(ka, va, vb, n)                                  \
    ka = *(const float4*)(Khs + (n) * CC + 4 * cg2);        \
    va = *(const float4*)(Vs + (n) * CC + 4 * dg2);         \
    vb = *(const float4*)(Vs + (n) * CC + 64 + 4 * dg2);
#define P2F(ka, va, vb)                                     \
    {  float kc[4] = {ka.x, ka.y, ka.z, ka.w};              \
       float vd[8] = {va.x, va.y, va.z, va.w,               \
                      vb.x, vb.y, vb.z, vb.w};              \
       _Pragma("unroll")                                    \
       for (int i = 0; i < 4; i++)                          \
           { _Pragma("unroll")                              \
             for (int j = 0; j < 8; j++)                    \
                 a2[i][j] += kc[i] * vd[j]; } }

        {
            float4 kaA, vaA, vbA, kaB, vaB, vbB;
            P2L(kaA, vaA, vbA, 0)
            for (int n = 0; n <= 60; n += 2) {
                P2L(kaB, vaB, vbB, n + 1)
                P2F(kaA, vaA, vbA)
                P2L(kaA, vaA, vbA, n + 2)
                P2F(kaB, vaB, vbB)
            }
            P2L(kaB, vaB, vbB, 63)
            P2F(kaA, vaA, vbA)
            P2F(kaB, vaB, vbB)
        }
#undef P2L
#undef P2F

        float* pp = ws + PP_OFF + (size_t)blk * (CC * CC);
#pragma unroll
        for (int i = 0; i < 4; i++) {
            int c = 4 * cg2 + i;
            *(float4*)(pp + c * CC + 4 * dg2) =
                make_float4(a2[i][0], a2[i][1], a2[i][2], a2[i][3]);
            *(float4*)(pp + c * CC + 64 + 4 * dg2) =
                make_float4(a2[i][4], a2[i][5], a2[i][6], a2[i][7]);
        }

        red[nrv * 32 + c4v] = ksum4;
        __syncthreads();
        if (tid < 32) {
            float4 sm = red[tid];
#pragma unroll
            for (int i = 1; i < 16; i++) {
                float4 t = red[i * 32 + tid];
                sm.x += t.x; sm.y += t.y; sm.z += t.z; sm.w += t.w;
            }
            ((float4*)(ws + KP_OFF + (size_t)blk * CC))[tid] = sm;
        }
    }

    grid_barrier(bar);

    // ======================= Phase B: reduce + M-build =====================
    {
        float4* W4s   = (float4*)S;          // 4096 float4 = 64 KB
        float*  m0p   = (float*)red;         // 4 x 128
        float*  kpart = m0p + 512;           // 2
        float*  ksl   = kpart + 2;           // 2
        float*  m0row = ksl + 2;             // 2 x 128

        const int x = blk & 63, b2 = blk >> 6;
        const int c0 = x * 2;

        for (int idx = tid; idx < CC * 32; idx += 512) {
            int e = idx >> 5, d4 = idx & 31;
            W4s[(e << 5) + (d4 ^ (e & 31))] = ((const float4*)W)[idx];
        }

        // reduce 2 rows of M0 over 64 partials, split 2 ways over partials
        {
            const int r2 = tid >> 7;           // 0..3
            const int r = r2 & 1, h = r2 >> 1;
            const int d = tid & 127;
            const float* pp = ws + PP_OFF
                            + (size_t)(b2 * 64 + h * 32) * (CC * CC)
                            + (size_t)(c0 + r) * CC + d;
            float a0 = 0.f, a1 = 0.f, a2 = 0.f, a3 = 0.f;
#pragma unroll 8
            for (int p = 0; p < 32; p += 4) {
                a0 += pp[(size_t)(p + 0) * (CC * CC)];
                a1 += pp[(size_t)(p + 1) * (CC * CC)];
                a2 += pp[(size_t)(p + 2) * (CC * CC)];
                a3 += pp[(size_t)(p + 3) * (CC * CC)];
            }
            m0p[r2 * CC + d] = (a0 + a1) + (a2 + a3);
        }

        // reduce 2 Ksum entries over 64 partials (one wave each)
        if (tid < 128) {
            const int rr = tid >> 6, p = tid & 63;
            float v = ws[KP_OFF + (size_t)(b2 * 64 + p) * CC + c0 + rr];
#pragma unroll
            for (int off = 32; off > 0; off >>= 1) v += __shfl_xor(v, off, 64);
            if ((tid & 63) == 0) kpart[rr] = v;
        }
        __syncthreads();

        if (tid < 256) {
            const int r = tid >> 7, d = tid & 127;
            m0row[r * CC + d] = m0p[r * CC + d] + m0p[(r + 2) * CC + d];
        }
        if (tid < 2) {
            ksl[tid] = kpart[tid];
            ws[KS_OFF + b2 * CC + c0 + tid] = kpart[tid];
        }
        __syncthreads();

        // M = M0 @ W^T + Ksum b^T
        if (tid < 256) {
            const int r = tid >> 7, e = tid & 127;
            const float4* mr = (const float4*)(m0row + r * CC);
            float m = 0.f;
#pragma unroll
            for (int d4 = 0; d4 < 32; d4++) {
                float4 a4 = mr[d4];
                float4 w4 = W4s[(e << 5) + (d4 ^ (e & 31))];
                m += a4.x * w4.x + a4.y * w4.y + a4.z * w4.z + a4.w * w4.w;
            }
            m += ksl[r] * bias[e];
            ws[MM_OFF + (size_t)b2 * CC * CC + (size_t)(c0 + r) * CC + e] = m;
        }
    }

    grid_barrier(bar + 1);

    // ======================= Phase C: output GEMM ==========================
    {
        const int b = blk >> 6;
        const int r0 = (blk & 63) * 64;
        const float* M = ws + MM_OFF + (size_t)b * CC * CC;

        for (int e = tid; e < CC * CC / 4; e += 512)
            ((float4*)S)[e] = ((const float4*)M)[e];

        const float4* Ks4 = (const float4*)(ws + KS_OFF + b * CC);
        const int dg = tid & 31, rg = tid >> 5;   // rg 0..15, 4 rows each
        const int row = r0 + rg * 4;
        const float4* Qv = (const float4*)(ws + QP_OFF + ((size_t)b * NN + row) * CC);
        const float4* Mv = (const float4*)S;

        float4 acc[4];
        float s[4];
#pragma unroll
        for (int i = 0; i < 4; i++) {
            acc[i] = make_float4(0.f, 0.f, 0.f, 0.f);
            s[i] = 0.f;
        }

        __syncthreads();

#define OLW(m0, m1, m2, m3, ks, c)               \
    m0 = Mv[(((c) + 0) << 5) + dg];              \
    m1 = Mv[(((c) + 1) << 5) + dg];              \
    m2 = Mv[(((c) + 2) << 5) + dg];              \
    m3 = Mv[(((c) + 3) << 5) + dg];              \
    ks = Ks4[(c) >> 2];
#define OLX(xv, c)                                 \
    { const int c4_ = (c) >> 2;                    \
      xv[0] = Qv[c4_];      xv[1] = Qv[32 + c4_];  \
      xv[2] = Qv[64 + c4_]; xv[3] = Qv[96 + c4_]; }
#define OFM(m0, m1, m2, m3, ks, xv)                  \
    _Pragma("unroll")                                \
    for (int i_ = 0; i_ < 4; i_++) {                 \
        fma4(acc[i_], xv[i_], m0, m1, m2, m3);       \
        s[i_] += dot4(xv[i_], ks);                   \
    }

        {
            float4 mA0, mA1, mA2, mA3, mB0, mB1, mB2, mB3;
            float4 ksA, ksB, xA[4], xB[4];
            OLW(mA0, mA1, mA2, mA3, ksA, 0)
            OLX(xA, 0)
            for (int c = 0; c <= CC - 16; c += 8) {
                OLW(mB0, mB1, mB2, mB3, ksB, c + 4)
                OLX(xB, c + 4)
                OFM(mA0, mA1, mA2, mA3, ksA, xA)
                OLW(mA0, mA1, mA2, mA3, ksA, c + 8)
                OLX(xA, c + 8)
                OFM(mB0, mB1, mB2, mB3, ksB, xB)
            }
            OLW(mB0, mB1, mB2, mB3, ksB, CC - 4)
            OLX(xB, CC - 4)
            OFM(mA0, mA1, mA2, mA3, ksA, xA)
            OFM(mB0, mB1, mB2, mB3, ksB, xB)
        }
#undef OLW
#undef OLX
#undef OFM

        float* op = out + ((size_t)b * NN + row) * CC;
        const float* qn = ws + QN_OFF + (size_t)b * NN + row;
#pragma unroll
        for (int i = 0; i < 4; i++) {
            float inv = 1.0f / (s[i] + 1e-8f * qn[i]);
            float4 o = acc[i];
            o.x *= inv; o.y *= inv; o.z *= inv; o.w *= inv;
            ((float4*)(op + (size_t)i * CC))[dg] = o;
        }
    }
}

// ---------------------------------------------------------------------------
extern "C" void kernel_launch(void* const* d_in, const int* in_sizes, int n_in,
                              void* d_out, int out_size, void* d_ws, size_t ws_size,
                              hipStream_t stream)
{
    const float* q_node = (const float*)d_in[0];
    const float* k_node = (const float*)d_in[1];
    const float* v_node = (const float*)d_in[2];
    const float* W      = (const float*)d_in[3];
    const float* bias   = (const float*)d_in[4];
    float* out = (float*)d_out;
    float* ws  = (float*)d_ws;

    // zero the two grid-barrier counters (graph-capturable)
    hipMemsetAsync(ws + BAR_OFF, 0, 2 * sizeof(unsigned), stream);

    fused_kernel<<<NBLK, 512, 0, stream>>>(q_node, k_node, v_node,
                                           W, bias, ws, out);
}

// Round 9
// 131.638 us; speedup vs baseline: 2.0688x; 2.0688x over previous
//
#include <hip/hip_runtime.h>

#define BB 4
#define NN 4096
#define CC 128
#define NROWS (BB * NN)   // 16384 rows per tensor

// workspace layout (float offsets)
#define QN_OFF  0                              // |q_proj| per row (16384)
#define QP_OFF  (QN_OFF + NROWS)               // projected q, 16384 x 128
#define MM_OFF  (QP_OFF + NROWS * CC)          // B x 128 x 128  M = M0 W^T + Ksum b^T
#define KS_OFF  (MM_OFF + BB * CC * CC)        // B x 128  Ksum (sum of khat rows)
#define PP_OFF  (KS_OFF + BB * CC)             // 256 x 16384 partial M0s
#define KP_OFF  (PP_OFF + 256 * CC * CC)       // 256 x 128 partial ksums

__device__ __forceinline__ void fma4(float4& a, const float4 x,
    const float4 w0, const float4 w1, const float4 w2, const float4 w3)
{
    a.x += x.x * w0.x + x.y * w1.x + x.z * w2.x + x.w * w3.x;
    a.y += x.x * w0.y + x.y * w1.y + x.z * w2.y + x.w * w3.y;
    a.z += x.x * w0.z + x.y * w1.z + x.z * w2.z + x.w * w3.z;
    a.w += x.x * w0.w + x.y * w1.w + x.z * w2.w + x.w * w3.w;
}

__device__ __forceinline__ float dot4(const float4 x, const float4 k)
{
    return x.x * k.x + x.y * k.y + x.z * k.z + x.w * k.w;
}

// ---------------------------------------------------------------------------
// Kernel 1 (R5, validated): fused projection + partial-M build.
// 256 blocks x 512 threads, 64 rows (q and k) per block, 8 row-accs per
// thread, rank-64 partial M0 + partial ksum. 2-stage register pipeline.
// ---------------------------------------------------------------------------
__global__ __launch_bounds__(512, 2) void projpb_kernel(
    const float* __restrict__ q_node, const float* __restrict__ k_node,
    const float* __restrict__ v_node, const float* __restrict__ W,
    const float* __restrict__ bias, float* __restrict__ ws)
{
    __shared__ float S[CC * CC];    // phase 1: swizzled W^T; phase 2: khat|v tiles
    __shared__ float4 red[512];
    const int tid = threadIdx.x;

    for (int e = tid; e < CC * CC; e += 512) {
        int d = e >> 7, c = e & 127;
        S[(c << 7) + ((((d >> 2) ^ (c & 31)) << 2) | (d & 3))] = W[e];
    }

    const int blk  = blockIdx.x;        // 0..255
    const int base = blk * 64;          // row base (same rows in q and k tensors)
    const int dg = tid & 31;            // output-dim group (4 dims)
    const int rg = tid >> 5;            // 0..15, 4 rows each

    float4 bias4 = ((const float4*)bias)[dg];
    float4 acc[8];                      // q0..q3, k0..k3
#pragma unroll
    for (int i = 0; i < 8; i++) acc[i] = bias4;

    __syncthreads();

    const float4* Qv = (const float4*)(q_node + (size_t)(base + rg * 4) * CC);
    const float4* Kv = (const float4*)(k_node + (size_t)(base + rg * 4) * CC);
    const float4* Sv = (const float4*)S;

#define LW(s0, s1, s2, s3, c)                              \
    s0 = Sv[(((c) + 0) << 5) + (dg ^ (((c) + 0) & 31))];   \
    s1 = Sv[(((c) + 1) << 5) + (dg ^ (((c) + 1) & 31))];   \
    s2 = Sv[(((c) + 2) << 5) + (dg ^ (((c) + 2) & 31))];   \
    s3 = Sv[(((c) + 3) << 5) + (dg ^ (((c) + 3) & 31))];
#define LX(xq, xk, c)                                      \
    { const int c4_ = (c) >> 2;                            \
      xq[0] = Qv[c4_];      xq[1] = Qv[32 + c4_];          \
      xq[2] = Qv[64 + c4_]; xq[3] = Qv[96 + c4_];          \
      xk[0] = Kv[c4_];      xk[1] = Kv[32 + c4_];          \
      xk[2] = Kv[64 + c4_]; xk[3] = Kv[96 + c4_]; }
#define FM(w0, w1, w2, w3, xq, xk)                         \
    fma4(acc[0], xq[0], w0, w1, w2, w3);                   \
    fma4(acc[1], xq[1], w0, w1, w2, w3);                   \
    fma4(acc[2], xq[2], w0, w1, w2, w3);                   \
    fma4(acc[3], xq[3], w0, w1, w2, w3);                   \
    fma4(acc[4], xk[0], w0, w1, w2, w3);                   \
    fma4(acc[5], xk[1], w0, w1, w2, w3);                   \
    fma4(acc[6], xk[2], w0, w1, w2, w3);                   \
    fma4(acc[7], xk[3], w0, w1, w2, w3);

    {
        float4 wA0, wA1, wA2, wA3, wB0, wB1, wB2, wB3;
        float4 xqA[4], xkA[4], xqB[4], xkB[4];

        LW(wA0, wA1, wA2, wA3, 0)
        LX(xqA, xkA, 0)
        for (int c = 0; c <= CC - 16; c += 8) {
            LW(wB0, wB1, wB2, wB3, c + 4)
            LX(xqB, xkB, c + 4)
            FM(wA0, wA1, wA2, wA3, xqA, xkA)
            LW(wA0, wA1, wA2, wA3, c + 8)
            LX(xqA, xkA, c + 8)
            FM(wB0, wB1, wB2, wB3, xqB, xkB)
        }
        LW(wB0, wB1, wB2, wB3, CC - 4)
        LX(xqB, xkB, CC - 4)
        FM(wA0, wA1, wA2, wA3, xqA, xkA)
        FM(wB0, wB1, wB2, wB3, xqB, xkB)
    }
#undef LW
#undef LX
#undef FM

    // q rows: store projected row + norm
#pragma unroll
    for (int i = 0; i < 4; i++) {
        const int rq = base + rg * 4 + i;
        float ss = acc[i].x * acc[i].x + acc[i].y * acc[i].y
                 + acc[i].z * acc[i].z + acc[i].w * acc[i].w;
#pragma unroll
        for (int off = 16; off > 0; off >>= 1) ss += __shfl_xor(ss, off, 32);
        ((float4*)(ws + QP_OFF + (size_t)rq * CC))[dg] = acc[i];
        if (dg == 0) ws[QN_OFF + rq] = sqrtf(ss);
    }

    __syncthreads();   // everyone done reading W before LDS reuse

    float* Khs = S;            // 64 x 128 (32 KB)
    float* Vs  = S + 8192;     // 64 x 128 (32 KB)

    // k rows: normalize into LDS
#pragma unroll
    for (int i = 0; i < 4; i++) {
        float ss = acc[4 + i].x * acc[4 + i].x + acc[4 + i].y * acc[4 + i].y
                 + acc[4 + i].z * acc[4 + i].z + acc[4 + i].w * acc[4 + i].w;
#pragma unroll
        for (int off = 16; off > 0; off >>= 1) ss += __shfl_xor(ss, off, 32);
        float inv = 1.0f / sqrtf(ss);
        float4 o = acc[4 + i];
        o.x *= inv; o.y *= inv; o.z *= inv; o.w *= inv;
        ((float4*)(Khs + (rg * 4 + i) * CC))[dg] = o;
    }

    // stage v rows 64x128 (each thread 4 float4)
    const int c4v = tid & 31, nrv = tid >> 5;   // nrv 0..15
    const float* Vp = v_node + (size_t)base * CC;
#pragma unroll
    for (int i = 0; i < 4; i++) {
        int n = nrv + i * 16;
        ((float4*)(Vs + n * CC))[c4v] = ((const float4*)(Vp + (size_t)n * CC))[c4v];
    }
    __syncthreads();

    // partial ksum (column sums of khat)
    float4 ksum4 = make_float4(0.f, 0.f, 0.f, 0.f);
#pragma unroll
    for (int i = 0; i < 4; i++) {
        int n = nrv + i * 16;
        float4 kv = ((const float4*)(Khs + n * CC))[c4v];
        ksum4.x += kv.x; ksum4.y += kv.y; ksum4.z += kv.z; ksum4.w += kv.w;
    }

    // rank-64 outer product, software-pipelined over n
    const int dg2 = tid & 15, cg = tid >> 4;    // cg 0..31
    float a2[4][8];
#pragma unroll
    for (int i = 0; i < 4; i++)
#pragma unroll
        for (int j = 0; j < 8; j++) a2[i][j] = 0.f;

#define P2L(ka, va, vb, n)                                  \
    ka = *(const float4*)(Khs + (n) * CC + 4 * cg);         \
    va = *(const float4*)(Vs + (n) * CC + 4 * dg2);         \
    vb = *(const float4*)(Vs + (n) * CC + 64 + 4 * dg2);
#define P2F(ka, va, vb)                                     \
    {  float kc[4] = {ka.x, ka.y, ka.z, ka.w};              \
       float vd[8] = {va.x, va.y, va.z, va.w,               \
                      vb.x, vb.y, vb.z, vb.w};              \
       _Pragma("unroll")                                    \
       for (int i = 0; i < 4; i++)                          \
           { _Pragma("unroll")                              \
             for (int j = 0; j < 8; j++)                    \
                 a2[i][j] += kc[i] * vd[j]; } }

    {
        float4 kaA, vaA, vbA, kaB, vaB, vbB;
        P2L(kaA, vaA, vbA, 0)
        for (int n = 0; n <= 60; n += 2) {
            P2L(kaB, vaB, vbB, n + 1)
            P2F(kaA, vaA, vbA)
            P2L(kaA, vaA, vbA, n + 2)
            P2F(kaB, vaB, vbB)
        }
        P2L(kaB, vaB, vbB, 63)
        P2F(kaA, vaA, vbA)
        P2F(kaB, vaB, vbB)
    }
#undef P2L
#undef P2F

    float* pp = ws + PP_OFF + (size_t)blk * (CC * CC);
#pragma unroll
    for (int i = 0; i < 4; i++) {
        int c = 4 * cg + i;
        *(float4*)(pp + c * CC + 4 * dg2) =
            make_float4(a2[i][0], a2[i][1], a2[i][2], a2[i][3]);
        *(float4*)(pp + c * CC + 64 + 4 * dg2) =
            make_float4(a2[i][4], a2[i][5], a2[i][6], a2[i][7]);
    }

    red[nrv * 32 + c4v] = ksum4;
    __syncthreads();
    if (tid < 32) {
        float4 sm = red[tid];
#pragma unroll
        for (int i = 1; i < 16; i++) {
            float4 t = red[i * 32 + tid];
            sm.x += t.x; sm.y += t.y; sm.z += t.z; sm.w += t.w;
        }
        ((float4*)(ws + KP_OFF + (size_t)blk * CC))[tid] = sm;
    }
}

// ---------------------------------------------------------------------------
// Kernel 2: fused reduce + M-build (64 partials per batch).
// M0 reduction now float4-vectorized: thread = (quarter q, row r, col4 c4),
// sums 16 partials as dwordx4 (was 64 scalar dwords), quarters combined in
// LDS. Same traffic, 4x fewer VMEM instructions.
// ---------------------------------------------------------------------------
__global__ __launch_bounds__(256) void mchain_kernel(const float* __restrict__ W,
                                                     const float* __restrict__ bias,
                                                     float* __restrict__ ws)
{
    __shared__ float4 W4s[CC * 32];    // W natural, float4-swizzled per row (64 KB)
    __shared__ float4 m0q[4][2][32];   // quarter partial sums (4 KB)
    __shared__ float m0row[2][CC];
    __shared__ float kpart[4];
    __shared__ float ksl[2];
    const int tid = threadIdx.x;
    const int b = blockIdx.y, x = blockIdx.x;
    const int c0 = x * 2;

    for (int idx = tid; idx < CC * 32; idx += 256) {
        int e = idx >> 5, d4 = idx & 31;
        W4s[(e << 5) + (d4 ^ (e & 31))] = ((const float4*)W)[idx];
    }

    // reduce 2 rows of M0 over 64 partials: 4-way quarter split, float4 loads
    {
        const int q  = tid >> 6;           // 0..3 partial quarter
        const int r  = (tid >> 5) & 1;     // row within pair
        const int c4 = tid & 31;           // float4 column
        const float4* pp = (const float4*)(ws + PP_OFF
                         + (size_t)(b * 64 + q * 16) * (CC * CC)
                         + (size_t)(c0 + r) * CC) + c4;
        float4 s0 = make_float4(0.f, 0.f, 0.f, 0.f);
#pragma unroll 4
        for (int p = 0; p < 16; p++) {
            float4 t = pp[(size_t)p * (CC * CC / 4)];
            s0.x += t.x; s0.y += t.y; s0.z += t.z; s0.w += t.w;
        }
        m0q[q][r][c4] = s0;
    }

    // reduce 2 Ksum entries over 64 partials
    {
        const int rr = tid >> 7, p = tid & 127;
        float v = 0.f;
        if (p < 64) v = ws[KP_OFF + (size_t)(b * 64 + p) * CC + c0 + rr];
#pragma unroll
        for (int off = 32; off > 0; off >>= 1) v += __shfl_xor(v, off, 64);
        if ((tid & 63) == 0) kpart[tid >> 6] = v;
    }
    __syncthreads();

    if (tid < 64) {
        const int r = tid >> 5, c4 = tid & 31;
        float4 a = m0q[0][r][c4], bq = m0q[1][r][c4];
        float4 c = m0q[2][r][c4], d = m0q[3][r][c4];
        float4 s;
        s.x = (a.x + bq.x) + (c.x + d.x);
        s.y = (a.y + bq.y) + (c.y + d.y);
        s.z = (a.z + bq.z) + (c.z + d.z);
        s.w = (a.w + bq.w) + (c.w + d.w);
        ((float4*)&m0row[r][0])[c4] = s;
    }
    if (tid < 2) {
        float s = kpart[tid * 2] + kpart[tid * 2 + 1];
        ksl[tid] = s;
        ws[KS_OFF + b * CC + c0 + tid] = s;
    }
    __syncthreads();

    // M = M0 @ W^T + Ksum b^T  (thread -> one output element)
    const int r = tid >> 7, e = tid & 127;
    const float4* mr = (const float4*)m0row[r];
    float m = 0.f;
#pragma unroll
    for (int d4 = 0; d4 < 32; d4++) {
        float4 a4 = mr[d4];                              // broadcast
        float4 w4 = W4s[(e << 5) + (d4 ^ (e & 31))];     // conflict-spread
        m += a4.x * w4.x + a4.y * w4.y + a4.z * w4.z + a4.w * w4.w;
    }
    m += ksl[r] * bias[e];
    ws[MM_OFF + (size_t)b * CC * CC + (size_t)(c0 + r) * CC + e] = m;
}

// ---------------------------------------------------------------------------
// Kernel 3 (R5, validated): out[b,r,:] =
//   (q_proj[r] @ M) / (q_proj[r].Ksum + 1e-8*|q_proj[r]|)
// 256 blocks x 512 threads, 64 rows per block, 4 row-accs per thread.
// ---------------------------------------------------------------------------
__global__ __launch_bounds__(512, 2) void out_kernel(const float* __restrict__ ws,
                                                     float* __restrict__ out)
{
    __shared__ float Ml[CC * CC];

    const int blk = blockIdx.x;     // 0..255
    const int b = blk >> 6;
    const int r0 = (blk & 63) * 64;
    const float* M = ws + MM_OFF + (size_t)b * CC * CC;
    const int tid = threadIdx.x;

    for (int e = tid; e < CC * CC / 4; e += 512)
        ((float4*)Ml)[e] = ((const float4*)M)[e];

    const float4* Ks4 = (const float4*)(ws + KS_OFF + b * CC);
    const int dg = tid & 31, rg = tid >> 5;   // rg 0..15, 4 rows each
    const int row = r0 + rg * 4;
    const float4* Qv = (const float4*)(ws + QP_OFF + ((size_t)b * NN + row) * CC);
    const float4* Mv = (const float4*)Ml;

    float4 acc[4];
    float s[4];
#pragma unroll
    for (int i = 0; i < 4; i++) {
        acc[i] = make_float4(0.f, 0.f, 0.f, 0.f);
        s[i] = 0.f;
    }

    __syncthreads();

#define OLW(m0, m1, m2, m3, ks, c)               \
    m0 = Mv[(((c) + 0) << 5) + dg];              \
    m1 = Mv[(((c) + 1) << 5) + dg];              \
    m2 = Mv[(((c) + 2) << 5) + dg];              \
    m3 = Mv[(((c) + 3) << 5) + dg];              \
    ks = Ks4[(c) >> 2];
#define OLX(xv, c)                                 \
    { const int c4_ = (c) >> 2;                    \
      xv[0] = Qv[c4_];      xv[1] = Qv[32 + c4_];  \
      xv[2] = Qv[64 + c4_]; xv[3] = Qv[96 + c4_]; }
#define OFM(m0, m1, m2, m3, ks, xv)                  \
    _Pragma("unroll")                                \
    for (int i_ = 0; i_ < 4; i_++) {                 \
        fma4(acc[i_], xv[i_], m0, m1, m2, m3);       \
        s[i_] += dot4(xv[i_], ks);                   \
    }

    {
        float4 mA0, mA1, mA2, mA3, mB0, mB1, mB2, mB3;
        float4 ksA, ksB, xA[4], xB[4];
        OLW(mA0, mA1, mA2, mA3, ksA, 0)
        OLX(xA, 0)
        for (int c = 0; c <= CC - 16; c += 8) {
            OLW(mB0, mB1, mB2, mB3, ksB, c + 4)
            OLX(xB, c + 4)
            OFM(mA0, mA1, mA2, mA3, ksA, xA)
            OLW(mA0, mA1, mA2, mA3, ksA, c + 8)
            OLX(xA, c + 8)
            OFM(mB0, mB1, mB2, mB3, ksB, xB)
        }
        OLW(mB0, mB1, mB2, mB3, ksB, CC - 4)
        OLX(xB, CC - 4)
        OFM(mA0, mA1, mA2, mA3, ksA, xA)
        OFM(mB0, mB1, mB2, mB3, ksB, xB)
    }
#undef OLW
#undef OLX
#undef OFM

    float* op = out + ((size_t)b * NN + row) * CC;
    const float* qn = ws + QN_OFF + (size_t)b * NN + row;
#pragma unroll
    for (int i = 0; i < 4; i++) {
        float inv = 1.0f / (s[i] + 1e-8f * qn[i]);
        float4 o = acc[i];
        o.x *= inv; o.y *= inv; o.z *= inv; o.w *= inv;
        ((float4*)(op + (size_t)i * CC))[dg] = o;
    }
}

// ---------------------------------------------------------------------------
extern "C" void kernel_launch(void* const* d_in, const int* in_sizes, int n_in,
                              void* d_out, int out_size, void* d_ws, size_t ws_size,
                              hipStream_t stream)
{
    const float* q_node = (const float*)d_in[0];
    const float* k_node = (const float*)d_in[1];
    const float* v_node = (const float*)d_in[2];
    const float* W      = (const float*)d_in[3];
    const float* bias   = (const float*)d_in[4];
    float* out = (float*)d_out;
    float* ws  = (float*)d_ws;

    projpb_kernel<<<256, 512, 0, stream>>>(q_node, k_node, v_node, W, bias, ws);
    mchain_kernel<<<dim3(64, BB), 256, 0, stream>>>(W, bias, ws);
    out_kernel<<<256, 512, 0, stream>>>(ws, out);
}

// Round 11
// 121.281 us; speedup vs baseline: 2.2454x; 1.0854x over previous
//
#include <hip/hip_runtime.h>

#define BB 4
#define NN 4096
#define CC 128
#define NROWS (BB * NN)   // 16384 rows per tensor

// workspace layout (float offsets)
#define QN_OFF  0                              // |q_proj| per row (16384)
#define QP_OFF  (QN_OFF + NROWS)               // projected q, 16384 x 128
#define MM_OFF  (QP_OFF + NROWS * CC)          // B x 128 x 128  M = M0 W^T + Ksum b^T
#define KS_OFF  (MM_OFF + BB * CC * CC)        // B x 128  Ksum (sum of khat rows)
#define PP_OFF  (KS_OFF + BB * CC)             // 256 x 16384 partial M0s
#define KP_OFF  (PP_OFF + 256 * CC * CC)       // 256 x 128 partial ksums

typedef __attribute__((ext_vector_type(8))) short short8;
typedef __attribute__((ext_vector_type(4))) float f32x4;

__device__ __forceinline__ void fma4(float4& a, const float4 x,
    const float4 w0, const float4 w1, const float4 w2, const float4 w3)
{
    a.x += x.x * w0.x + x.y * w1.x + x.z * w2.x + x.w * w3.x;
    a.y += x.x * w0.y + x.y * w1.y + x.z * w2.y + x.w * w3.y;
    a.z += x.x * w0.z + x.y * w1.z + x.z * w2.z + x.w * w3.z;
    a.w += x.x * w0.w + x.y * w1.w + x.z * w2.w + x.w * w3.w;
}

__device__ __forceinline__ float dot4(const float4 x, const float4 k)
{
    return x.x * k.x + x.y * k.y + x.z * k.z + x.w * k.w;
}

__device__ __forceinline__ unsigned short f2bf(float f)
{
    union { float f; unsigned u; } v; v.f = f;
    unsigned r = (v.u + 0x7fffu + ((v.u >> 16) & 1u)) >> 16;   // RNE
    return (unsigned short)r;
}
__device__ __forceinline__ float bf2f(unsigned short h)
{
    union { unsigned u; float f; } v; v.u = ((unsigned)h) << 16;
    return v.f;
}

// ---------------------------------------------------------------------------
// Kernel 1: fused projection (3-way-split bf16 MFMA, ~2^-27 precision) +
// partial-M build (fp32 VALU). 256 blocks x 512 threads (8 waves).
// Waves 0-3: 64 q rows; waves 4-7: 64 k rows. Per wave: 16-row tile x 128
// outdims via mfma_f32_16x16x32_bf16, 6-term hi/mid/lo split:
//   x = hi + mid + lo (each bf16); keep hh, hm, mh, hl, mm, lh terms;
//   dropped terms are O(2^-27) -> fp32-class accuracy.
// W staged in LDS as 3 bf16 planes with 16B-slot XOR swizzle.
// Phase 2 (rank-64 outer product) identical to validated R9.
// ---------------------------------------------------------------------------
__global__ __launch_bounds__(512, 1) void projpb_kernel(
    const float* __restrict__ q_node, const float* __restrict__ k_node,
    const float* __restrict__ v_node, const float* __restrict__ W,
    const float* __restrict__ bias, float* __restrict__ ws)
{
    __shared__ __align__(16) unsigned short Wsp[3 * CC * CC];  // 96 KB
    __shared__ float4 red[512];                                 // 8 KB
    unsigned short* Whi = Wsp;                 // [col][swizzled k] 128x128
    unsigned short* Wmd = Wsp + CC * CC;
    unsigned short* Wlo = Wsp + 2 * CC * CC;

    const int tid = threadIdx.x;

    // stage W as 3-way split bf16. B[col][k] = W^T[k][col] = W[col][k].
    // per col: 16 slots of 8 bf16; slot = (k>>3) ^ (col&7).
    for (int e = tid; e < CC * CC; e += 512) {
        int col = e >> 7, k = e & 127;
        float wv = W[e];
        unsigned short hi = f2bf(wv);
        float r1 = wv - bf2f(hi);
        unsigned short md = f2bf(r1);
        unsigned short lo = f2bf(r1 - bf2f(md));
        int idx = (col << 7) + ((((k >> 3) ^ (col & 7)) << 3) | (k & 7));
        Whi[idx] = hi; Wmd[idx] = md; Wlo[idx] = lo;
    }

    const int blk  = blockIdx.x;      // 0..255
    const int base = blk * 64;
    const int w    = tid >> 6;        // wave 0..7
    const int lane = tid & 63;
    const int l15  = lane & 15;       // A-row / B-col / C-col within tile
    const int lg   = lane >> 4;       // k-group 0..3
    const bool isq = (w < 4);
    const int rt   = w & 3;           // row-tile within its tensor
    const float* X = isq ? q_node : k_node;
    const int arow = base + rt * 16 + l15;   // this lane's A row (global)

    f32x4 acc[8];
#pragma unroll
    for (int ct = 0; ct < 8; ct++) {
        float b = bias[ct * 16 + l15];
        acc[ct] = (f32x4){b, b, b, b};
    }

    __syncthreads();   // W staged

    const float* Xr = X + (size_t)arow * CC;
#pragma unroll
    for (int ks = 0; ks < 4; ks++) {
        const int k0 = ks * 32 + lg * 8;
        float4 xa = *(const float4*)(Xr + k0);
        float4 xb = *(const float4*)(Xr + k0 + 4);
        float xs[8] = {xa.x, xa.y, xa.z, xa.w, xb.x, xb.y, xb.z, xb.w};
        short8 Ahi, Amd, Alo;
#pragma unroll
        for (int j = 0; j < 8; j++) {
            unsigned short h = f2bf(xs[j]);
            float r1 = xs[j] - bf2f(h);
            unsigned short m = f2bf(r1);
            Ahi[j] = (short)h;
            Amd[j] = (short)m;
            Alo[j] = (short)f2bf(r1 - bf2f(m));
        }
        const int slot = ks * 4 + lg;      // k0 >> 3
#pragma unroll
        for (int ct = 0; ct < 8; ct++) {
            int col  = ct * 16 + l15;
            int fidx = (col << 7) + ((slot ^ (col & 7)) << 3);
            short8 Bhi = *(const short8*)(Whi + fidx);
            short8 Bmd = *(const short8*)(Wmd + fidx);
            short8 Blo = *(const short8*)(Wlo + fidx);
            acc[ct] = __builtin_amdgcn_mfma_f32_16x16x32_bf16(Ahi, Bhi, acc[ct], 0, 0, 0);
            acc[ct] = __builtin_amdgcn_mfma_f32_16x16x32_bf16(Ahi, Bmd, acc[ct], 0, 0, 0);
            acc[ct] = __builtin_amdgcn_mfma_f32_16x16x32_bf16(Amd, Bhi, acc[ct], 0, 0, 0);
            acc[ct] = __builtin_amdgcn_mfma_f32_16x16x32_bf16(Ahi, Blo, acc[ct], 0, 0, 0);
            acc[ct] = __builtin_amdgcn_mfma_f32_16x16x32_bf16(Amd, Bmd, acc[ct], 0, 0, 0);
            acc[ct] = __builtin_amdgcn_mfma_f32_16x16x32_bf16(Alo, Bhi, acc[ct], 0, 0, 0);
        }
    }

    // C/D layout (HW-verified): col = lane&15, row = (lane>>4)*4 + reg.
    float ss[4];
#pragma unroll
    for (int r = 0; r < 4; r++) {
        float t = 0.f;
#pragma unroll
        for (int ct = 0; ct < 8; ct++) t += acc[ct][r] * acc[ct][r];
#pragma unroll
        for (int off = 8; off > 0; off >>= 1) t += __shfl_xor(t, off, 16);
        ss[r] = t;
    }

    if (isq) {
#pragma unroll
        for (int r = 0; r < 4; r++) {
            int gr = base + rt * 16 + lg * 4 + r;
            float* qp = ws + QP_OFF + (size_t)gr * CC;
#pragma unroll
            for (int ct = 0; ct < 8; ct++) qp[ct * 16 + l15] = acc[ct][r];
            if (l15 == 0) ws[QN_OFF + gr] = sqrtf(ss[r]);
        }
    }

    __syncthreads();   // all waves done reading W LDS before overwrite

    float* Khs = (float*)Wsp;          // 64 x 128 f32 (32 KB)
    float* Vs  = Khs + 8192;           // 64 x 128 f32 (32 KB)

    if (!isq) {
#pragma unroll
        for (int r = 0; r < 4; r++) {
            float inv = 1.0f / sqrtf(ss[r]);
            int lr = rt * 16 + lg * 4 + r;       // local k row 0..63
            float* kp = Khs + lr * CC;
#pragma unroll
            for (int ct = 0; ct < 8; ct++) kp[ct * 16 + l15] = acc[ct][r] * inv;
        }
    }

    // stage v rows 64x128 (each thread 4 float4)
    const int c4v = tid & 31, nrv = tid >> 5;   // nrv 0..15
    const float* Vp = v_node + (size_t)base * CC;
#pragma unroll
    for (int i = 0; i < 4; i++) {
        int n = nrv + i * 16;
        ((float4*)(Vs + n * CC))[c4v] = ((const float4*)(Vp + (size_t)n * CC))[c4v];
    }
    __syncthreads();

    // partial ksum (column sums of khat)
    float4 ksum4 = make_float4(0.f, 0.f, 0.f, 0.f);
#pragma unroll
    for (int i = 0; i < 4; i++) {
        int n = nrv + i * 16;
        float4 kv = ((const float4*)(Khs + n * CC))[c4v];
        ksum4.x += kv.x; ksum4.y += kv.y; ksum4.z += kv.z; ksum4.w += kv.w;
    }

    // rank-64 outer product, software-pipelined over n (validated R5/R9)
    const int dg2 = tid & 15, cg = tid >> 4;    // cg 0..31
    float a2[4][8];
#pragma unroll
    for (int i = 0; i < 4; i++)
#pragma unroll
        for (int j = 0; j < 8; j++) a2[i][j] = 0.f;

#define P2L(ka, va, vb, n)                                  \
    ka = *(const float4*)(Khs + (n) * CC + 4 * cg);         \
    va = *(const float4*)(Vs + (n) * CC + 4 * dg2);         \
    vb = *(const float4*)(Vs + (n) * CC + 64 + 4 * dg2);
#define P2F(ka, va, vb)                                     \
    {  float kc[4] = {ka.x, ka.y, ka.z, ka.w};              \
       float vd[8] = {va.x, va.y, va.z, va.w,               \
                      vb.x, vb.y, vb.z, vb.w};              \
       _Pragma("unroll")                                    \
       for (int i = 0; i < 4; i++)                          \
           { _Pragma("unroll")                              \
             for (int j = 0; j < 8; j++)                    \
                 a2[i][j] += kc[i] * vd[j]; } }

    {
        float4 kaA, vaA, vbA, kaB, vaB, vbB;
        P2L(kaA, vaA, vbA, 0)
        for (int n = 0; n <= 60; n += 2) {
            P2L(kaB, vaB, vbB, n + 1)
            P2F(kaA, vaA, vbA)
            P2L(kaA, vaA, vbA, n + 2)
            P2F(kaB, vaB, vbB)
        }
        P2L(kaB, vaB, vbB, 63)
        P2F(kaA, vaA, vbA)
        P2F(kaB, vaB, vbB)
    }
#undef P2L
#undef P2F

    float* pp = ws + PP_OFF + (size_t)blk * (CC * CC);
#pragma unroll
    for (int i = 0; i < 4; i++) {
        int c = 4 * cg + i;
        *(float4*)(pp + c * CC + 4 * dg2) =
            make_float4(a2[i][0], a2[i][1], a2[i][2], a2[i][3]);
        *(float4*)(pp + c * CC + 64 + 4 * dg2) =
            make_float4(a2[i][4], a2[i][5], a2[i][6], a2[i][7]);
    }

    red[nrv * 32 + c4v] = ksum4;
    __syncthreads();
    if (tid < 32) {
        float4 sm = red[tid];
#pragma unroll
        for (int i = 1; i < 16; i++) {
            float4 t = red[i * 32 + tid];
            sm.x += t.x; sm.y += t.y; sm.z += t.z; sm.w += t.w;
        }
        ((float4*)(ws + KP_OFF + (size_t)blk * CC))[tid] = sm;
    }
}

// ---------------------------------------------------------------------------
// Kernel 2 (R9, validated): fused reduce + M-build, float4-vectorized.
// ---------------------------------------------------------------------------
__global__ __launch_bounds__(256) void mchain_kernel(const float* __restrict__ W,
                                                     const float* __restrict__ bias,
                                                     float* __restrict__ ws)
{
    __shared__ float4 W4s[CC * 32];    // W natural, float4-swizzled per row (64 KB)
    __shared__ float4 m0q[4][2][32];   // quarter partial sums (4 KB)
    __shared__ float m0row[2][CC];
    __shared__ float kpart[4];
    __shared__ float ksl[2];
    const int tid = threadIdx.x;
    const int b = blockIdx.y, x = blockIdx.x;
    const int c0 = x * 2;

    for (int idx = tid; idx < CC * 32; idx += 256) {
        int e = idx >> 5, d4 = idx & 31;
        W4s[(e << 5) + (d4 ^ (e & 31))] = ((const float4*)W)[idx];
    }

    // reduce 2 rows of M0 over 64 partials: 4-way quarter split, float4 loads
    {
        const int q  = tid >> 6;           // 0..3 partial quarter
        const int r  = (tid >> 5) & 1;     // row within pair
        const int c4 = tid & 31;           // float4 column
        const float4* pp = (const float4*)(ws + PP_OFF
                         + (size_t)(b * 64 + q * 16) * (CC * CC)
                         + (size_t)(c0 + r) * CC) + c4;
        float4 s0 = make_float4(0.f, 0.f, 0.f, 0.f);
#pragma unroll 4
        for (int p = 0; p < 16; p++) {
            float4 t = pp[(size_t)p * (CC * CC / 4)];
            s0.x += t.x; s0.y += t.y; s0.z += t.z; s0.w += t.w;
        }
        m0q[q][r][c4] = s0;
    }

    // reduce 2 Ksum entries over 64 partials
    {
        const int rr = tid >> 7, p = tid & 127;
        float v = 0.f;
        if (p < 64) v = ws[KP_OFF + (size_t)(b * 64 + p) * CC + c0 + rr];
#pragma unroll
        for (int off = 32; off > 0; off >>= 1) v += __shfl_xor(v, off, 64);
        if ((tid & 63) == 0) kpart[tid >> 6] = v;
    }
    __syncthreads();

    if (tid < 64) {
        const int r = tid >> 5, c4 = tid & 31;
        float4 a = m0q[0][r][c4], bq = m0q[1][r][c4];
        float4 c = m0q[2][r][c4], d = m0q[3][r][c4];
        float4 s;
        s.x = (a.x + bq.x) + (c.x + d.x);
        s.y = (a.y + bq.y) + (c.y + d.y);
        s.z = (a.z + bq.z) + (c.z + d.z);
        s.w = (a.w + bq.w) + (c.w + d.w);
        ((float4*)&m0row[r][0])[c4] = s;
    }
    if (tid < 2) {
        float s = kpart[tid * 2] + kpart[tid * 2 + 1];
        ksl[tid] = s;
        ws[KS_OFF + b * CC + c0 + tid] = s;
    }
    __syncthreads();

    // M = M0 @ W^T + Ksum b^T  (thread -> one output element)
    const int r = tid >> 7, e = tid & 127;
    const float4* mr = (const float4*)m0row[r];
    float m = 0.f;
#pragma unroll
    for (int d4 = 0; d4 < 32; d4++) {
        float4 a4 = mr[d4];                              // broadcast
        float4 w4 = W4s[(e << 5) + (d4 ^ (e & 31))];     // conflict-spread
        m += a4.x * w4.x + a4.y * w4.y + a4.z * w4.z + a4.w * w4.w;
    }
    m += ksl[r] * bias[e];
    ws[MM_OFF + (size_t)b * CC * CC + (size_t)(c0 + r) * CC + e] = m;
}

// ---------------------------------------------------------------------------
// Kernel 3 (R5/R9, validated): out[b,r,:] =
//   (q_proj[r] @ M) / (q_proj[r].Ksum + 1e-8*|q_proj[r]|)
// ---------------------------------------------------------------------------
__global__ __launch_bounds__(512, 2) void out_kernel(const float* __restrict__ ws,
                                                     float* __restrict__ out)
{
    __shared__ float Ml[CC * CC];

    const int blk = blockIdx.x;     // 0..255
    const int b = blk >> 6;
    const int r0 = (blk & 63) * 64;
    const float* M = ws + MM_OFF + (size_t)b * CC * CC;
    const int tid = threadIdx.x;

    for (int e = tid; e < CC * CC / 4; e += 512)
        ((float4*)Ml)[e] = ((const float4*)M)[e];

    const float4* Ks4 = (const float4*)(ws + KS_OFF + b * CC);
    const int dg = tid & 31, rg = tid >> 5;   // rg 0..15, 4 rows each
    const int row = r0 + rg * 4;
    const float4* Qv = (const float4*)(ws + QP_OFF + ((size_t)b * NN + row) * CC);
    const float4* Mv = (const float4*)Ml;

    float4 acc[4];
    float s[4];
#pragma unroll
    for (int i = 0; i < 4; i++) {
        acc[i] = make_float4(0.f, 0.f, 0.f, 0.f);
        s[i] = 0.f;
    }

    __syncthreads();

#define OLW(m0, m1, m2, m3, ks, c)               \
    m0 = Mv[(((c) + 0) << 5) + dg];              \
    m1 = Mv[(((c) + 1) << 5) + dg];              \
    m2 = Mv[(((c) + 2) << 5) + dg];              \
    m3 = Mv[(((c) + 3) << 5) + dg];              \
    ks = Ks4[(c) >> 2];
#define OLX(xv, c)                                 \
    { const int c4_ = (c) >> 2;                    \
      xv[0] = Qv[c4_];      xv[1] = Qv[32 + c4_];  \
      xv[2] = Qv[64 + c4_]; xv[3] = Qv[96 + c4_]; }
#define OFM(m0, m1, m2, m3, ks, xv)                  \
    _Pragma("unroll")                                \
    for (int i_ = 0; i_ < 4; i_++) {                 \
        fma4(acc[i_], xv[i_], m0, m1, m2, m3);       \
        s[i_] += dot4(xv[i_], ks);                   \
    }

    {
        float4 mA0, mA1, mA2, mA3, mB0, mB1, mB2, mB3;
        float4 ksA, ksB, xA[4], xB[4];
        OLW(mA0, mA1, mA2, mA3, ksA, 0)
        OLX(xA, 0)
        for (int c = 0; c <= CC - 16; c += 8) {
            OLW(mB0, mB1, mB2, mB3, ksB, c + 4)
            OLX(xB, c + 4)
            OFM(mA0, mA1, mA2, mA3, ksA, xA)
            OLW(mA0, mA1, mA2, mA3, ksA, c + 8)
            OLX(xA, c + 8)
            OFM(mB0, mB1, mB2, mB3, ksB, xB)
        }
        OLW(mB0, mB1, mB2, mB3, ksB, CC - 4)
        OLX(xB, CC - 4)
        OFM(mA0, mA1, mA2, mA3, ksA, xA)
        OFM(mB0, mB1, mB2, mB3, ksB, xB)
    }
#undef OLW
#undef OLX
#undef OFM

    float* op = out + ((size_t)b * NN + row) * CC;
    const float* qn = ws + QN_OFF + (size_t)b * NN + row;
#pragma unroll
    for (int i = 0; i < 4; i++) {
        float inv = 1.0f / (s[i] + 1e-8f * qn[i]);
        float4 o = acc[i];
        o.x *= inv; o.y *= inv; o.z *= inv; o.w *= inv;
        ((float4*)(op + (size_t)i * CC))[dg] = o;
    }
}

// ---------------------------------------------------------------------------
extern "C" void kernel_launch(void* const* d_in, const int* in_sizes, int n_in,
                              void* d_out, int out_size, void* d_ws, size_t ws_size,
                              hipStream_t stream)
{
    const float* q_node = (const float*)d_in[0];
    const float* k_node = (const float*)d_in[1];
    const float* v_node = (const float*)d_in[2];
    const float* W      = (const float*)d_in[3];
    const float* bias   = (const float*)d_in[4];
    float* out = (float*)d_out;
    float* ws  = (float*)d_ws;

    projpb_kernel<<<256, 512, 0, stream>>>(q_node, k_node, v_node, W, bias, ws);
    mchain_kernel<<<dim3(64, BB), 256, 0, stream>>>(W, bias, ws);
    out_kernel<<<256, 512, 0, stream>>>(ws, out);
}